// Round 2
// 583.590 us; speedup vs baseline: 1.1311x; 1.1311x over previous
//
#include <hip/hip_runtime.h>

typedef _Float16 h16;
typedef __attribute__((ext_vector_type(4))) _Float16 h16x4;
typedef __attribute__((ext_vector_type(8))) _Float16 h16x8;
typedef __attribute__((ext_vector_type(4))) float f32x4;

#define NQD 4194304L   // 16384 * 256
#define NROWS 16384L
#define NKK 4096L

static __device__ __forceinline__ f32x4 mfma16(h16x8 a, h16x8 b, f32x4 c) {
  return __builtin_amdgcn_mfma_f32_16x16x32_f16(a, b, c, 0, 0, 0);
}

// ---------------- cast 6 weight matrices fp32 -> f16 ----------------
__global__ void cast_weights(const float* __restrict__ w0, const float* __restrict__ w1,
                             const float* __restrict__ w2, const float* __restrict__ w3,
                             const float* __restrict__ w4, const float* __restrict__ w5,
                             h16* __restrict__ dst) {
  int wi = blockIdx.y;
  const float* src = wi == 0 ? w0 : wi == 1 ? w1 : wi == 2 ? w2 : wi == 3 ? w3 : wi == 4 ? w4 : w5;
  int c = blockIdx.x * 256 + threadIdx.x;
  float4 v = ((const float4*)src)[c];
  h16x4 h = {(h16)v.x, (h16)v.y, (h16)v.z, (h16)v.w};
  *(h16x4*)&dst[(long)wi * 65536 + (long)c * 4] = h;
}

// ---------------- fused Q/K/V projection: z picks operand set ----------------
// grid(128, 4, 3), block 256. Tile 128x64, BK=64.
// z==2 (V): output transposed vT[b][d][k] via LDS restage, coalesced h16x8 stores.
__global__ __launch_bounds__(256) void qkv_proj(const float* __restrict__ x,
                                                const float* __restrict__ qry,
                                                const h16* __restrict__ wh,
                                                const float* __restrict__ bq,
                                                const float* __restrict__ bk,
                                                const float* __restrict__ bv,
                                                h16* __restrict__ qh,
                                                h16* __restrict__ kh,
                                                h16* __restrict__ vT) {
  const int z = blockIdx.z;
  const float* A = (z == 0) ? qry : x;
  const h16* W = wh + (long)z * 65536;
  const float* bias = (z == 0) ? bq : (z == 1) ? bk : bv;
  h16* outH = (z == 0) ? qh : (z == 1) ? kh : nullptr;
  h16* outT = (z == 2) ? vT : nullptr;

  __shared__ h16 smem[128 * 72 + 64 * 72];
  h16 (*As)[72] = (h16(*)[72])smem;
  h16 (*Bs)[72] = (h16(*)[72])(smem + 128 * 72);
  const int tid = threadIdx.x;
  const int wave = tid >> 6, lane = tid & 63;
  const int quad = lane >> 4, l16 = lane & 15;
  const long arow0 = (long)blockIdx.x * 128;
  const int bn = blockIdx.y;
  f32x4 acc[2][4] = {};
  for (int k0 = 0; k0 < 256; k0 += 64) {
    #pragma unroll
    for (int it = 0; it < 8; ++it) {
      int c = it * 256 + tid;
      int r = c >> 4, c4 = (c & 15) * 4;
      float4 v = *(const float4*)&A[(arow0 + r) * 256 + k0 + c4];
      h16x4 h = {(h16)v.x, (h16)v.y, (h16)v.z, (h16)v.w};
      *(h16x4*)&As[r][c4] = h;
    }
    #pragma unroll
    for (int it = 0; it < 2; ++it) {
      int c = it * 256 + tid;
      int r = c >> 3, c8 = (c & 7) * 8;
      *(h16x8*)&Bs[r][c8] = *(const h16x8*)&W[(long)(bn * 64 + r) * 256 + k0 + c8];
    }
    __syncthreads();
    #pragma unroll
    for (int ks = 0; ks < 64; ks += 32) {
      h16x8 a[2], b[4];
      #pragma unroll
      for (int mi = 0; mi < 2; ++mi)
        a[mi] = *(const h16x8*)&As[wave * 32 + mi * 16 + l16][ks + quad * 8];
      #pragma unroll
      for (int ni = 0; ni < 4; ++ni)
        b[ni] = *(const h16x8*)&Bs[ni * 16 + l16][ks + quad * 8];
      #pragma unroll
      for (int mi = 0; mi < 2; ++mi)
        #pragma unroll
        for (int ni = 0; ni < 4; ++ni)
          acc[mi][ni] = mfma16(a[mi], b[ni], acc[mi][ni]);
    }
    __syncthreads();
  }
  if (outH) {
    #pragma unroll
    for (int mi = 0; mi < 2; ++mi) {
      #pragma unroll
      for (int ni = 0; ni < 4; ++ni) {
        int n = bn * 64 + ni * 16 + l16;
        float bv_ = bias[n];
        #pragma unroll
        for (int i = 0; i < 4; ++i) {
          long m = arow0 + wave * 32 + mi * 16 + quad * 4 + i;
          outH[m * 256 + n] = (h16)(acc[mi][ni][i] + bv_);
        }
      }
    }
  } else {
    // restage transposed: stg[d(64)][k(128)], stride 136 to spread banks
    h16* stg = smem;
    #pragma unroll
    for (int mi = 0; mi < 2; ++mi) {
      #pragma unroll
      for (int ni = 0; ni < 4; ++ni) {
        int dl = ni * 16 + l16;
        float bv_ = bias[bn * 64 + dl];
        int mlb = wave * 32 + mi * 16 + quad * 4;
        h16x4 hv = {(h16)(acc[mi][ni][0] + bv_), (h16)(acc[mi][ni][1] + bv_),
                    (h16)(acc[mi][ni][2] + bv_), (h16)(acc[mi][ni][3] + bv_)};
        *(h16x4*)&stg[dl * 136 + mlb] = hv;
      }
    }
    __syncthreads();
    const int bb = (int)(arow0 >> 12);
    const long kb = arow0 & 4095;
    #pragma unroll
    for (int p = 0; p < 4; ++p) {
      int d = p * 16 + (tid >> 4);
      int c = (tid & 15) * 8;
      h16x8 v = *(const h16x8*)&stg[d * 136 + c];
      *(h16x8*)&outT[((long)bb * 256 + bn * 64 + d) * 4096 + kb + c] = v;
    }
  }
}

// ---------------- plain 256-K GEMM for MLP ----------------
__global__ __launch_bounds__(256) void gemm256(const h16* __restrict__ A,
                                               const h16* __restrict__ W,
                                               const float* __restrict__ bias,
                                               h16* __restrict__ outH,
                                               float* __restrict__ outF) {
  __shared__ h16 As[128][72];
  __shared__ h16 Bs[64][72];
  const int tid = threadIdx.x;
  const int wave = tid >> 6, lane = tid & 63;
  const int quad = lane >> 4, l16 = lane & 15;
  const long arow0 = (long)blockIdx.x * 128;
  const int bn = blockIdx.y;
  f32x4 acc[2][4] = {};
  for (int k0 = 0; k0 < 256; k0 += 64) {
    #pragma unroll
    for (int it = 0; it < 4; ++it) {
      int c = it * 256 + tid;
      int r = c >> 3, c8 = (c & 7) * 8;
      *(h16x8*)&As[r][c8] = *(const h16x8*)&A[(arow0 + r) * 256 + k0 + c8];
    }
    #pragma unroll
    for (int it = 0; it < 2; ++it) {
      int c = it * 256 + tid;
      int r = c >> 3, c8 = (c & 7) * 8;
      *(h16x8*)&Bs[r][c8] = *(const h16x8*)&W[(long)(bn * 64 + r) * 256 + k0 + c8];
    }
    __syncthreads();
    #pragma unroll
    for (int ks = 0; ks < 64; ks += 32) {
      h16x8 a[2], b[4];
      #pragma unroll
      for (int mi = 0; mi < 2; ++mi)
        a[mi] = *(const h16x8*)&As[wave * 32 + mi * 16 + l16][ks + quad * 8];
      #pragma unroll
      for (int ni = 0; ni < 4; ++ni)
        b[ni] = *(const h16x8*)&Bs[ni * 16 + l16][ks + quad * 8];
      #pragma unroll
      for (int mi = 0; mi < 2; ++mi)
        #pragma unroll
        for (int ni = 0; ni < 4; ++ni)
          acc[mi][ni] = mfma16(a[mi], b[ni], acc[mi][ni]);
    }
    __syncthreads();
  }
  #pragma unroll
  for (int mi = 0; mi < 2; ++mi) {
    #pragma unroll
    for (int ni = 0; ni < 4; ++ni) {
      int n = bn * 64 + ni * 16 + l16;
      float bv = bias[n];
      #pragma unroll
      for (int i = 0; i < 4; ++i) {
        long m = arow0 + wave * 32 + mi * 16 + quad * 4 + i;
        float v = fmaxf(acc[mi][ni][i] + bv, 0.0f);
        if (outH) outH[m * 256 + n] = (h16)v;
        if (outF) outF[m * 256 + n] = v;
      }
    }
  }
}

// ---------------- scores: S = qk^T/16 (raw), + per-tile row stats ----------------
// grid(32, 32, 4), block 256. Tile 128x128, BK=64.
// f16 S is written via LDS restage -> coalesced h16x8 stores.
__global__ __launch_bounds__(256) void gemm_scores(const h16* __restrict__ qh,
                                                   const h16* __restrict__ kh,
                                                   float2* __restrict__ stats,
                                                   h16* __restrict__ Sh,
                                                   float* __restrict__ Sf) {
  __shared__ h16 smem[128 * 72 * 2];
  h16 (*As)[72] = (h16(*)[72])smem;
  h16 (*Bs)[72] = (h16(*)[72])(smem + 128 * 72);
  const int tid = threadIdx.x;
  const int wave = tid >> 6, lane = tid & 63;
  const int quad = lane >> 4, l16 = lane & 15;
  const int bm = blockIdx.x, bn = blockIdx.y, b = blockIdx.z;
  const h16* Aq = qh + (long)b * 4096 * 256 + (long)bm * 128 * 256;
  const h16* Bk = kh + (long)b * 4096 * 256 + (long)bn * 128 * 256;
  f32x4 acc[2][8] = {};
  for (int k0 = 0; k0 < 256; k0 += 64) {
    #pragma unroll
    for (int it = 0; it < 4; ++it) {
      int c = it * 256 + tid;
      int r = c >> 3, c8 = (c & 7) * 8;
      *(h16x8*)&As[r][c8] = *(const h16x8*)&Aq[(long)r * 256 + k0 + c8];
      *(h16x8*)&Bs[r][c8] = *(const h16x8*)&Bk[(long)r * 256 + k0 + c8];
    }
    __syncthreads();
    #pragma unroll
    for (int ks = 0; ks < 64; ks += 32) {
      h16x8 a[2], bb[8];
      #pragma unroll
      for (int mi = 0; mi < 2; ++mi)
        a[mi] = *(const h16x8*)&As[wave * 32 + mi * 16 + l16][ks + quad * 8];
      #pragma unroll
      for (int ni = 0; ni < 8; ++ni)
        bb[ni] = *(const h16x8*)&Bs[ni * 16 + l16][ks + quad * 8];
      #pragma unroll
      for (int mi = 0; mi < 2; ++mi)
        #pragma unroll
        for (int ni = 0; ni < 8; ++ni)
          acc[mi][ni] = mfma16(a[mi], bb[ni], acc[mi][ni]);
    }
    __syncthreads();
  }
  // scale
  #pragma unroll
  for (int mi = 0; mi < 2; ++mi)
    #pragma unroll
    for (int ni = 0; ni < 8; ++ni)
      #pragma unroll
      for (int i = 0; i < 4; ++i)
        acc[mi][ni][i] *= 0.0625f;
  // per-row stats: max over 128 cols, expsum relative to it
  #pragma unroll
  for (int mi = 0; mi < 2; ++mi) {
    #pragma unroll
    for (int i = 0; i < 4; ++i) {
      float mx = -1e30f;
      #pragma unroll
      for (int ni = 0; ni < 8; ++ni) mx = fmaxf(mx, acc[mi][ni][i]);
      #pragma unroll
      for (int off = 1; off < 16; off <<= 1) mx = fmaxf(mx, __shfl_xor(mx, off));
      float es = 0.0f;
      #pragma unroll
      for (int ni = 0; ni < 8; ++ni) es += __expf(acc[mi][ni][i] - mx);
      #pragma unroll
      for (int off = 1; off < 16; off <<= 1) es += __shfl_xor(es, off);
      if (l16 == 0) {
        long row = (long)b * 4096 + bm * 128 + wave * 32 + mi * 16 + quad * 4 + i;
        stats[row * 32 + bn] = make_float2(mx, es);
      }
    }
  }
  if (Sh) {
    // restage the 128x128 f16 tile in LDS (reuse GEMM smem), then coalesced write
    h16* stg = smem;   // [128][136]
    #pragma unroll
    for (int mi = 0; mi < 2; ++mi) {
      #pragma unroll
      for (int ni = 0; ni < 8; ++ni) {
        int c = ni * 16 + l16;
        #pragma unroll
        for (int i = 0; i < 4; ++i) {
          int r = wave * 32 + mi * 16 + quad * 4 + i;
          stg[r * 136 + c] = (h16)acc[mi][ni][i];
        }
      }
    }
    __syncthreads();
    const long rowbase = (long)b * 4096 + (long)bm * 128;
    const long colbase = (long)bn * 128;
    #pragma unroll
    for (int p = 0; p < 8; ++p) {
      int r = p * 16 + (tid >> 4);
      int c = (tid & 15) * 8;
      h16x8 v = *(const h16x8*)&stg[r * 136 + c];
      *(h16x8*)&Sh[(rowbase + r) * 4096 + colbase + c] = v;
    }
  } else {
    #pragma unroll
    for (int mi = 0; mi < 2; ++mi) {
      #pragma unroll
      for (int ni = 0; ni < 8; ++ni) {
        long col = (long)bn * 128 + ni * 16 + l16;
        #pragma unroll
        for (int i = 0; i < 4; ++i) {
          long row = (long)b * 4096 + bm * 128 + wave * 32 + mi * 16 + quad * 4 + i;
          Sf[row * 4096 + col] = acc[mi][ni][i];
        }
      }
    }
  }
}

// ---------------- av: fused rowstats + normalize raw S on the fly, write attn, O = P @ vT^T ----------------
// grid(256, KS), block 256 (4 waves). Tile M=64, N=256, BK=32, K-chunk 4096/KS.
template <typename TS>
__global__ __launch_bounds__(256, 4) void gemm_av(const TS* __restrict__ S,
                                                  const h16* __restrict__ vT,
                                                  const float2* __restrict__ stats,
                                                  float* __restrict__ attn,
                                                  float* __restrict__ Opart,
                                                  h16* __restrict__ Odirect,
                                                  int KS) {
  __shared__ h16 As[64][40];
  __shared__ h16 Bs[256][40];
  __shared__ float2 rs[64];
  const int tid = threadIdx.x;
  const int wave = tid >> 6, lane = tid & 63;
  const int quad = lane >> 4, l16 = lane & 15;
  const int mb = blockIdx.x, kc = blockIdx.y;
  const int KB = 4096 / KS;
  const long row0 = (long)mb * 64;
  const int b = mb >> 6;
  const h16* Vb = vT + (long)b * 256 * 4096;

  // ---- fused rowstats: merge 32 tile-stats per row -> (m, 1/l) for this block's 64 rows ----
  {
    int r = tid >> 2, j = tid & 3;
    const float2* sp = stats + (row0 + r) * 32 + j * 8;
    float2 sv[8];
    float m = -1e30f;
    #pragma unroll
    for (int t = 0; t < 8; ++t) { sv[t] = sp[t]; m = fmaxf(m, sv[t].x); }
    m = fmaxf(m, __shfl_xor(m, 1));
    m = fmaxf(m, __shfl_xor(m, 2));
    float e = 0.0f;
    #pragma unroll
    for (int t = 0; t < 8; ++t) e += sv[t].y * __expf(sv[t].x - m);
    e += __shfl_xor(e, 1);
    e += __shfl_xor(e, 2);
    if (j == 0) rs[r] = make_float2(m, 1.0f / e);
  }
  __syncthreads();

  // staging assignment: fixed row per thread
  const int sr = tid >> 2, sc = (tid & 3) * 8;
  const long srow = row0 + sr;
  const float2 st = rs[sr];
  const TS* Srow = S + srow * 4096;
  float* Arow = attn + srow * 4096;

  f32x4 acc[4][4] = {};
  const int kbeg = kc * KB, kend = kbeg + KB;
  for (int k0 = kbeg; k0 < kend; k0 += 32) {
    // ---- A: load raw s, p = exp(s-m)*invl, write attn (nontemporal), stage f16 p ----
    float p[8];
    if constexpr (sizeof(TS) == 2) {
      h16x8 sv = *(const h16x8*)&Srow[k0 + sc];
      #pragma unroll
      for (int e = 0; e < 8; ++e) p[e] = __expf((float)sv[e] - st.x) * st.y;
    } else {
      float4 sa = *(const float4*)&Srow[k0 + sc];
      float4 sb = *(const float4*)&Srow[k0 + sc + 4];
      p[0] = __expf(sa.x - st.x) * st.y; p[1] = __expf(sa.y - st.x) * st.y;
      p[2] = __expf(sa.z - st.x) * st.y; p[3] = __expf(sa.w - st.x) * st.y;
      p[4] = __expf(sb.x - st.x) * st.y; p[5] = __expf(sb.y - st.x) * st.y;
      p[6] = __expf(sb.z - st.x) * st.y; p[7] = __expf(sb.w - st.x) * st.y;
    }
    f32x4 w0 = {p[0], p[1], p[2], p[3]}, w1 = {p[4], p[5], p[6], p[7]};
    __builtin_nontemporal_store(w0, (f32x4*)&Arow[k0 + sc]);
    __builtin_nontemporal_store(w1, (f32x4*)&Arow[k0 + sc + 4]);
    h16x8 ph = {(h16)p[0], (h16)p[1], (h16)p[2], (h16)p[3],
                (h16)p[4], (h16)p[5], (h16)p[6], (h16)p[7]};
    *(h16x8*)&As[sr][sc] = ph;
    // ---- B: vT rows (d) x 32 k ----
    #pragma unroll
    for (int it = 0; it < 4; ++it) {
      int d = it * 64 + (tid >> 2);
      *(h16x8*)&Bs[d][sc] = *(const h16x8*)&Vb[(long)d * 4096 + k0 + sc];
    }
    __syncthreads();
    h16x8 a[4], bb[4];
    #pragma unroll
    for (int mi = 0; mi < 4; ++mi)
      a[mi] = *(const h16x8*)&As[mi * 16 + l16][quad * 8];
    #pragma unroll
    for (int ni = 0; ni < 4; ++ni)
      bb[ni] = *(const h16x8*)&Bs[wave * 64 + ni * 16 + l16][quad * 8];
    #pragma unroll
    for (int mi = 0; mi < 4; ++mi)
      #pragma unroll
      for (int ni = 0; ni < 4; ++ni)
        acc[mi][ni] = mfma16(a[mi], bb[ni], acc[mi][ni]);
    __syncthreads();
  }
  #pragma unroll
  for (int mi = 0; mi < 4; ++mi) {
    #pragma unroll
    for (int ni = 0; ni < 4; ++ni) {
      int col = wave * 64 + ni * 16 + l16;
      #pragma unroll
      for (int i = 0; i < 4; ++i) {
        long row = row0 + mi * 16 + quad * 4 + i;
        if (Opart) Opart[((long)kc * NROWS + row) * 256 + col] = acc[mi][ni][i];
        else       Odirect[row * 256 + col] = (h16)acc[mi][ni][i];
      }
    }
  }
}

// ---------------- sum 4 K-split partials -> oh f16 ----------------
__global__ __launch_bounds__(256) void reduce_O(const float* __restrict__ Opart,
                                                h16* __restrict__ oh) {
  long i4 = (long)blockIdx.x * 256 + threadIdx.x;   // float4 chunk over 16384*256
  float4 s = {0, 0, 0, 0};
  #pragma unroll
  for (int kc = 0; kc < 4; ++kc) {
    float4 t = *(const float4*)&Opart[kc * NQD + i4 * 4];
    s.x += t.x; s.y += t.y; s.z += t.z; s.w += t.w;
  }
  h16x4 h = {(h16)s.x, (h16)s.y, (h16)s.z, (h16)s.w};
  *(h16x4*)&oh[i4 * 4] = h;
}

extern "C" void kernel_launch(void* const* d_in, const int* in_sizes, int n_in,
                              void* d_out, int out_size, void* d_ws, size_t ws_size,
                              hipStream_t stream) {
  (void)in_sizes; (void)n_in; (void)out_size;
  const float* x   = (const float*)d_in[0];
  const float* qry = (const float*)d_in[1];
  const float* Wq  = (const float*)d_in[2];  const float* bq = (const float*)d_in[3];
  const float* Wk  = (const float*)d_in[4];  const float* bk = (const float*)d_in[5];
  const float* Wv  = (const float*)d_in[6];  const float* bv = (const float*)d_in[7];
  const float* W1  = (const float*)d_in[8];  const float* b1 = (const float*)d_in[9];
  const float* W2  = (const float*)d_in[10]; const float* b2 = (const float*)d_in[11];
  const float* W3  = (const float*)d_in[12]; const float* b3 = (const float*)d_in[13];

  float* outH = (float*)d_out;
  float* attn = outH + NQD;

  char* w = (char*)d_ws;
  h16* qh = (h16*)w;
  h16* kh = qh + NQD;
  h16* vT = kh + NQD;
  h16* oh = vT + NQD;
  h16* h1 = oh + NQD;
  h16* h2 = h1 + NQD;
  h16* wh = h2 + NQD;                               // 6 x 65536 h16
  size_t off_rs   = (size_t)(6 * NQD + 6 * 65536) * 2;   // 51,118,080
  size_t BASE     = off_rs + NROWS * 8;                  // 51,249,152 (rowstats slot kept, unused)
  size_t statsB   = NROWS * 32 * 8;                      // 4 MiB
  size_t ShB      = NROWS * NKK * 2;                     // 128 MiB
  size_t OpartB   = 4 * NQD * 4;                         // 64 MiB

  bool modeA = ws_size >= BASE + statsB + ShB + OpartB;
  bool modeB = !modeA && ws_size >= BASE + statsB + OpartB;

  float2* stats    = (modeA || modeB) ? (float2*)(w + BASE) : (float2*)h1;
  h16*    Sh       = modeA ? (h16*)(w + BASE + statsB) : nullptr;
  float*  Opart    = modeA ? (float*)(w + BASE + statsB + ShB)
                   : modeB ? (float*)(w + BASE + statsB) : nullptr;
  int KS = (modeA || modeB) ? 4 : 1;

  cast_weights<<<dim3(64, 6), 256, 0, stream>>>(Wq, Wk, Wv, W1, W2, W3, wh);
  qkv_proj<<<dim3(128, 4, 3), 256, 0, stream>>>(x, qry, wh, bq, bk, bv, qh, kh, vT);
  gemm_scores<<<dim3(32, 32, 4), 256, 0, stream>>>(qh, kh, stats, Sh, modeA ? nullptr : attn);
  if (modeA)
    gemm_av<h16><<<dim3(256, KS), 256, 0, stream>>>(Sh, vT, stats, attn, Opart, oh, KS);
  else
    gemm_av<float><<<dim3(256, KS), 256, 0, stream>>>(attn, vT, stats, attn, Opart, oh, KS);
  if (Opart)
    reduce_O<<<dim3(4096), 256, 0, stream>>>(Opart, oh);
  gemm256<<<dim3(128, 4), 256, 0, stream>>>(oh, wh + 3 * 65536, b1, h1, nullptr);
  gemm256<<<dim3(128, 4), 256, 0, stream>>>(h1, wh + 4 * 65536, b2, h2, nullptr);
  gemm256<<<dim3(128, 4), 256, 0, stream>>>(h2, wh + 5 * 65536, b3, nullptr, outH);
}

// Round 4
// 550.344 us; speedup vs baseline: 1.1994x; 1.0604x over previous
//
#include <hip/hip_runtime.h>

typedef _Float16 h16;
typedef __attribute__((ext_vector_type(4))) _Float16 h16x4;
typedef __attribute__((ext_vector_type(8))) _Float16 h16x8;
typedef __attribute__((ext_vector_type(4))) float f32x4;

#define NQD 4194304L   // 16384 * 256
#define NROWS 16384L
#define NKK 4096L

static __device__ __forceinline__ f32x4 mfma16(h16x8 a, h16x8 b, f32x4 c) {
  return __builtin_amdgcn_mfma_f32_16x16x32_f16(a, b, c, 0, 0, 0);
}

// ---------------- cast 6 weight matrices fp32 -> f16 ----------------
__global__ void cast_weights(const float* __restrict__ w0, const float* __restrict__ w1,
                             const float* __restrict__ w2, const float* __restrict__ w3,
                             const float* __restrict__ w4, const float* __restrict__ w5,
                             h16* __restrict__ dst) {
  int wi = blockIdx.y;
  const float* src = wi == 0 ? w0 : wi == 1 ? w1 : wi == 2 ? w2 : wi == 3 ? w3 : wi == 4 ? w4 : w5;
  int c = blockIdx.x * 256 + threadIdx.x;
  float4 v = ((const float4*)src)[c];
  h16x4 h = {(h16)v.x, (h16)v.y, (h16)v.z, (h16)v.w};
  *(h16x4*)&dst[(long)wi * 65536 + (long)c * 4] = h;
}

// ---------------- fused Q/K/V projection: z picks operand set ----------------
// grid(128, 4, 3), block 256. Tile 128x64, BK=64.
// z==2 (V): output transposed vT[b][d][k] via LDS restage, coalesced h16x8 stores.
__global__ __launch_bounds__(256) void qkv_proj(const float* __restrict__ x,
                                                const float* __restrict__ qry,
                                                const h16* __restrict__ wh,
                                                const float* __restrict__ bq,
                                                const float* __restrict__ bk,
                                                const float* __restrict__ bv,
                                                h16* __restrict__ qh,
                                                h16* __restrict__ kh,
                                                h16* __restrict__ vT) {
  const int z = blockIdx.z;
  const float* A = (z == 0) ? qry : x;
  const h16* W = wh + (long)z * 65536;
  const float* bias = (z == 0) ? bq : (z == 1) ? bk : bv;
  h16* outH = (z == 0) ? qh : (z == 1) ? kh : nullptr;
  h16* outT = (z == 2) ? vT : nullptr;

  __shared__ h16 smem[128 * 72 + 64 * 72];
  h16 (*As)[72] = (h16(*)[72])smem;
  h16 (*Bs)[72] = (h16(*)[72])(smem + 128 * 72);
  const int tid = threadIdx.x;
  const int wave = tid >> 6, lane = tid & 63;
  const int quad = lane >> 4, l16 = lane & 15;
  const long arow0 = (long)blockIdx.x * 128;
  const int bn = blockIdx.y;
  f32x4 acc[2][4] = {};
  for (int k0 = 0; k0 < 256; k0 += 64) {
    #pragma unroll
    for (int it = 0; it < 8; ++it) {
      int c = it * 256 + tid;
      int r = c >> 4, c4 = (c & 15) * 4;
      float4 v = *(const float4*)&A[(arow0 + r) * 256 + k0 + c4];
      h16x4 h = {(h16)v.x, (h16)v.y, (h16)v.z, (h16)v.w};
      *(h16x4*)&As[r][c4] = h;
    }
    #pragma unroll
    for (int it = 0; it < 2; ++it) {
      int c = it * 256 + tid;
      int r = c >> 3, c8 = (c & 7) * 8;
      *(h16x8*)&Bs[r][c8] = *(const h16x8*)&W[(long)(bn * 64 + r) * 256 + k0 + c8];
    }
    __syncthreads();
    #pragma unroll
    for (int ks = 0; ks < 64; ks += 32) {
      h16x8 a[2], b[4];
      #pragma unroll
      for (int mi = 0; mi < 2; ++mi)
        a[mi] = *(const h16x8*)&As[wave * 32 + mi * 16 + l16][ks + quad * 8];
      #pragma unroll
      for (int ni = 0; ni < 4; ++ni)
        b[ni] = *(const h16x8*)&Bs[ni * 16 + l16][ks + quad * 8];
      #pragma unroll
      for (int mi = 0; mi < 2; ++mi)
        #pragma unroll
        for (int ni = 0; ni < 4; ++ni)
          acc[mi][ni] = mfma16(a[mi], b[ni], acc[mi][ni]);
    }
    __syncthreads();
  }
  if (outH) {
    #pragma unroll
    for (int mi = 0; mi < 2; ++mi) {
      #pragma unroll
      for (int ni = 0; ni < 4; ++ni) {
        int n = bn * 64 + ni * 16 + l16;
        float bv_ = bias[n];
        #pragma unroll
        for (int i = 0; i < 4; ++i) {
          long m = arow0 + wave * 32 + mi * 16 + quad * 4 + i;
          outH[m * 256 + n] = (h16)(acc[mi][ni][i] + bv_);
        }
      }
    }
  } else {
    // restage transposed: stg[d(64)][k(128)], stride 136 to spread banks
    h16* stg = smem;
    #pragma unroll
    for (int mi = 0; mi < 2; ++mi) {
      #pragma unroll
      for (int ni = 0; ni < 4; ++ni) {
        int dl = ni * 16 + l16;
        float bv_ = bias[bn * 64 + dl];
        int mlb = wave * 32 + mi * 16 + quad * 4;
        h16x4 hv = {(h16)(acc[mi][ni][0] + bv_), (h16)(acc[mi][ni][1] + bv_),
                    (h16)(acc[mi][ni][2] + bv_), (h16)(acc[mi][ni][3] + bv_)};
        *(h16x4*)&stg[dl * 136 + mlb] = hv;
      }
    }
    __syncthreads();
    const int bb = (int)(arow0 >> 12);
    const long kb = arow0 & 4095;
    #pragma unroll
    for (int p = 0; p < 4; ++p) {
      int d = p * 16 + (tid >> 4);
      int c = (tid & 15) * 8;
      h16x8 v = *(const h16x8*)&stg[d * 136 + c];
      *(h16x8*)&outT[((long)bb * 256 + bn * 64 + d) * 4096 + kb + c] = v;
    }
  }
}

// ---------------- plain 256-K GEMM for MLP ----------------
__global__ __launch_bounds__(256) void gemm256(const h16* __restrict__ A,
                                               const h16* __restrict__ W,
                                               const float* __restrict__ bias,
                                               h16* __restrict__ outH,
                                               float* __restrict__ outF) {
  __shared__ h16 As[128][72];
  __shared__ h16 Bs[64][72];
  const int tid = threadIdx.x;
  const int wave = tid >> 6, lane = tid & 63;
  const int quad = lane >> 4, l16 = lane & 15;
  const long arow0 = (long)blockIdx.x * 128;
  const int bn = blockIdx.y;
  f32x4 acc[2][4] = {};
  for (int k0 = 0; k0 < 256; k0 += 64) {
    #pragma unroll
    for (int it = 0; it < 4; ++it) {
      int c = it * 256 + tid;
      int r = c >> 3, c8 = (c & 7) * 8;
      *(h16x8*)&As[r][c8] = *(const h16x8*)&A[(arow0 + r) * 256 + k0 + c8];
    }
    #pragma unroll
    for (int it = 0; it < 2; ++it) {
      int c = it * 256 + tid;
      int r = c >> 3, c8 = (c & 7) * 8;
      *(h16x8*)&Bs[r][c8] = *(const h16x8*)&W[(long)(bn * 64 + r) * 256 + k0 + c8];
    }
    __syncthreads();
    #pragma unroll
    for (int ks = 0; ks < 64; ks += 32) {
      h16x8 a[2], b[4];
      #pragma unroll
      for (int mi = 0; mi < 2; ++mi)
        a[mi] = *(const h16x8*)&As[wave * 32 + mi * 16 + l16][ks + quad * 8];
      #pragma unroll
      for (int ni = 0; ni < 4; ++ni)
        b[ni] = *(const h16x8*)&Bs[ni * 16 + l16][ks + quad * 8];
      #pragma unroll
      for (int mi = 0; mi < 2; ++mi)
        #pragma unroll
        for (int ni = 0; ni < 4; ++ni)
          acc[mi][ni] = mfma16(a[mi], b[ni], acc[mi][ni]);
    }
    __syncthreads();
  }
  #pragma unroll
  for (int mi = 0; mi < 2; ++mi) {
    #pragma unroll
    for (int ni = 0; ni < 4; ++ni) {
      int n = bn * 64 + ni * 16 + l16;
      float bv = bias[n];
      #pragma unroll
      for (int i = 0; i < 4; ++i) {
        long m = arow0 + wave * 32 + mi * 16 + quad * 4 + i;
        float v = fmaxf(acc[mi][ni][i] + bv, 0.0f);
        if (outH) outH[m * 256 + n] = (h16)v;
        if (outF) outF[m * 256 + n] = v;
      }
    }
  }
}

// ---------------- scores: S = qk^T/16 (raw), + per-tile row stats ----------------
// grid(32, 32, 4), block 256. Tile 128x128, BK=64.
// f16 S is written via LDS restage -> coalesced h16x8 stores.
__global__ __launch_bounds__(256) void gemm_scores(const h16* __restrict__ qh,
                                                   const h16* __restrict__ kh,
                                                   float2* __restrict__ stats,
                                                   h16* __restrict__ Sh,
                                                   float* __restrict__ Sf) {
  __shared__ h16 smem[128 * 72 * 2];
  h16 (*As)[72] = (h16(*)[72])smem;
  h16 (*Bs)[72] = (h16(*)[72])(smem + 128 * 72);
  const int tid = threadIdx.x;
  const int wave = tid >> 6, lane = tid & 63;
  const int quad = lane >> 4, l16 = lane & 15;
  const int bm = blockIdx.x, bn = blockIdx.y, b = blockIdx.z;
  const h16* Aq = qh + (long)b * 4096 * 256 + (long)bm * 128 * 256;
  const h16* Bk = kh + (long)b * 4096 * 256 + (long)bn * 128 * 256;
  f32x4 acc[2][8] = {};
  for (int k0 = 0; k0 < 256; k0 += 64) {
    #pragma unroll
    for (int it = 0; it < 4; ++it) {
      int c = it * 256 + tid;
      int r = c >> 3, c8 = (c & 7) * 8;
      *(h16x8*)&As[r][c8] = *(const h16x8*)&Aq[(long)r * 256 + k0 + c8];
      *(h16x8*)&Bs[r][c8] = *(const h16x8*)&Bk[(long)r * 256 + k0 + c8];
    }
    __syncthreads();
    #pragma unroll
    for (int ks = 0; ks < 64; ks += 32) {
      h16x8 a[2], bb[8];
      #pragma unroll
      for (int mi = 0; mi < 2; ++mi)
        a[mi] = *(const h16x8*)&As[wave * 32 + mi * 16 + l16][ks + quad * 8];
      #pragma unroll
      for (int ni = 0; ni < 8; ++ni)
        bb[ni] = *(const h16x8*)&Bs[ni * 16 + l16][ks + quad * 8];
      #pragma unroll
      for (int mi = 0; mi < 2; ++mi)
        #pragma unroll
        for (int ni = 0; ni < 8; ++ni)
          acc[mi][ni] = mfma16(a[mi], bb[ni], acc[mi][ni]);
    }
    __syncthreads();
  }
  // scale
  #pragma unroll
  for (int mi = 0; mi < 2; ++mi)
    #pragma unroll
    for (int ni = 0; ni < 8; ++ni)
      #pragma unroll
      for (int i = 0; i < 4; ++i)
        acc[mi][ni][i] *= 0.0625f;
  // per-row stats: max over 128 cols, expsum relative to it
  #pragma unroll
  for (int mi = 0; mi < 2; ++mi) {
    #pragma unroll
    for (int i = 0; i < 4; ++i) {
      float mx = -1e30f;
      #pragma unroll
      for (int ni = 0; ni < 8; ++ni) mx = fmaxf(mx, acc[mi][ni][i]);
      #pragma unroll
      for (int off = 1; off < 16; off <<= 1) mx = fmaxf(mx, __shfl_xor(mx, off));
      float es = 0.0f;
      #pragma unroll
      for (int ni = 0; ni < 8; ++ni) es += __expf(acc[mi][ni][i] - mx);
      #pragma unroll
      for (int off = 1; off < 16; off <<= 1) es += __shfl_xor(es, off);
      if (l16 == 0) {
        long row = (long)b * 4096 + bm * 128 + wave * 32 + mi * 16 + quad * 4 + i;
        stats[row * 32 + bn] = make_float2(mx, es);
      }
    }
  }
  if (Sh) {
    // restage the 128x128 f16 tile in LDS (reuse GEMM smem), then coalesced write
    h16* stg = smem;   // [128][136]
    #pragma unroll
    for (int mi = 0; mi < 2; ++mi) {
      #pragma unroll
      for (int ni = 0; ni < 8; ++ni) {
        int c = ni * 16 + l16;
        #pragma unroll
        for (int i = 0; i < 4; ++i) {
          int r = wave * 32 + mi * 16 + quad * 4 + i;
          stg[r * 136 + c] = (h16)acc[mi][ni][i];
        }
      }
    }
    __syncthreads();
    const long rowbase = (long)b * 4096 + (long)bm * 128;
    const long colbase = (long)bn * 128;
    #pragma unroll
    for (int p = 0; p < 8; ++p) {
      int r = p * 16 + (tid >> 4);
      int c = (tid & 15) * 8;
      h16x8 v = *(const h16x8*)&stg[r * 136 + c];
      *(h16x8*)&Sh[(rowbase + r) * 4096 + colbase + c] = v;
    }
  } else {
    #pragma unroll
    for (int mi = 0; mi < 2; ++mi) {
      #pragma unroll
      for (int ni = 0; ni < 8; ++ni) {
        long col = (long)bn * 128 + ni * 16 + l16;
        #pragma unroll
        for (int i = 0; i < 4; ++i) {
          long row = (long)b * 4096 + bm * 128 + wave * 32 + mi * 16 + quad * 4 + i;
          Sf[row * 4096 + col] = acc[mi][ni][i];
        }
      }
    }
  }
}

// ---------------- av: fused rowstats + normalize raw S on the fly, write attn, O = P @ vT^T ----------------
// grid(256), block 512 (8 waves). Tile M=64, N=256, BK=64, full K=4096 per block (no split).
// Register-prefetch pipeline: stage(t) -> issue loads(t+1) -> barrier -> MFMA(t) -> barrier.
template <typename TS>
__global__ __launch_bounds__(512, 2) void gemm_av(const TS* __restrict__ S,
                                                  const h16* __restrict__ vT,
                                                  const float2* __restrict__ stats,
                                                  float* __restrict__ attn,
                                                  h16* __restrict__ oh) {
  __shared__ h16 As[64][72];
  __shared__ h16 Bs[256][72];
  __shared__ float2 rs[64];
  const int tid = threadIdx.x;
  const int wave = tid >> 6, lane = tid & 63;
  const int quad = lane >> 4, l16 = lane & 15;
  const int mb = blockIdx.x;
  const long row0 = (long)mb * 64;
  const int b = mb >> 6;
  const h16* Vb = vT + (long)b * 256 * 4096;

  // ---- fused rowstats: merge 32 tile-stats per row -> (m, 1/l) for this block's 64 rows ----
  {
    int r = tid >> 3, j = tid & 7;
    const float2* sp = stats + (row0 + r) * 32 + j * 4;
    float2 sv4[4];
    float m = -1e30f;
    #pragma unroll
    for (int t = 0; t < 4; ++t) { sv4[t] = sp[t]; m = fmaxf(m, sv4[t].x); }
    m = fmaxf(m, __shfl_xor(m, 1));
    m = fmaxf(m, __shfl_xor(m, 2));
    m = fmaxf(m, __shfl_xor(m, 4));
    float e = 0.0f;
    #pragma unroll
    for (int t = 0; t < 4; ++t) e += sv4[t].y * __expf(sv4[t].x - m);
    e += __shfl_xor(e, 1);
    e += __shfl_xor(e, 2);
    e += __shfl_xor(e, 4);
    if (j == 0) rs[r] = make_float2(m, 1.0f / e);
  }
  __syncthreads();

  // staging assignment: 8 threads per row, h16x8 chunks
  const int sr = tid >> 3, sc = (tid & 7) * 8;
  const long srow = row0 + sr;
  const float2 st = rs[sr];
  const TS* Srow = S + srow * 4096;
  float* Arow = attn + srow * 4096;
  const int vd = tid >> 3;            // V row within 64-row group

  f32x4 acc[4][2] = {};

  // ---- prologue: load k0=0 operands into registers ----
  h16x8 sv; float4 sa, sb;
  h16x8 bv0, bv1, bv2, bv3;
  if constexpr (sizeof(TS) == 2) {
    sv = *(const h16x8*)&Srow[sc];
  } else {
    sa = *(const float4*)&Srow[sc];
    sb = *(const float4*)&Srow[sc + 4];
  }
  bv0 = *(const h16x8*)&Vb[(long)(vd)       * 4096 + sc];
  bv1 = *(const h16x8*)&Vb[(long)(vd + 64)  * 4096 + sc];
  bv2 = *(const h16x8*)&Vb[(long)(vd + 128) * 4096 + sc];
  bv3 = *(const h16x8*)&Vb[(long)(vd + 192) * 4096 + sc];

  for (int k0 = 0; k0 < 4096; k0 += 64) {
    // ---- stage: p = exp(s-m)*invl, write attn (nontemporal), As/Bs to LDS ----
    float p[8];
    if constexpr (sizeof(TS) == 2) {
      #pragma unroll
      for (int e = 0; e < 8; ++e) p[e] = __expf((float)sv[e] - st.x) * st.y;
    } else {
      p[0] = __expf(sa.x - st.x) * st.y; p[1] = __expf(sa.y - st.x) * st.y;
      p[2] = __expf(sa.z - st.x) * st.y; p[3] = __expf(sa.w - st.x) * st.y;
      p[4] = __expf(sb.x - st.x) * st.y; p[5] = __expf(sb.y - st.x) * st.y;
      p[6] = __expf(sb.z - st.x) * st.y; p[7] = __expf(sb.w - st.x) * st.y;
    }
    f32x4 w0 = {p[0], p[1], p[2], p[3]}, w1 = {p[4], p[5], p[6], p[7]};
    __builtin_nontemporal_store(w0, (f32x4*)&Arow[k0 + sc]);
    __builtin_nontemporal_store(w1, (f32x4*)&Arow[k0 + sc + 4]);
    h16x8 ph = {(h16)p[0], (h16)p[1], (h16)p[2], (h16)p[3],
                (h16)p[4], (h16)p[5], (h16)p[6], (h16)p[7]};
    *(h16x8*)&As[sr][sc] = ph;
    *(h16x8*)&Bs[vd][sc]       = bv0;
    *(h16x8*)&Bs[vd + 64][sc]  = bv1;
    *(h16x8*)&Bs[vd + 128][sc] = bv2;
    *(h16x8*)&Bs[vd + 192][sc] = bv3;
    // ---- prefetch next tile into registers (in flight during MFMA) ----
    int kn = k0 + 64;
    if (kn < 4096) {
      if constexpr (sizeof(TS) == 2) {
        sv = *(const h16x8*)&Srow[kn + sc];
      } else {
        sa = *(const float4*)&Srow[kn + sc];
        sb = *(const float4*)&Srow[kn + sc + 4];
      }
      bv0 = *(const h16x8*)&Vb[(long)(vd)       * 4096 + kn + sc];
      bv1 = *(const h16x8*)&Vb[(long)(vd + 64)  * 4096 + kn + sc];
      bv2 = *(const h16x8*)&Vb[(long)(vd + 128) * 4096 + kn + sc];
      bv3 = *(const h16x8*)&Vb[(long)(vd + 192) * 4096 + kn + sc];
    }
    __syncthreads();
    // ---- MFMA over this BK=64 tile ----
    #pragma unroll
    for (int ks = 0; ks < 64; ks += 32) {
      h16x8 a[4], bb[2];
      #pragma unroll
      for (int mi = 0; mi < 4; ++mi)
        a[mi] = *(const h16x8*)&As[mi * 16 + l16][ks + quad * 8];
      #pragma unroll
      for (int ni = 0; ni < 2; ++ni)
        bb[ni] = *(const h16x8*)&Bs[wave * 32 + ni * 16 + l16][ks + quad * 8];
      #pragma unroll
      for (int mi = 0; mi < 4; ++mi)
        #pragma unroll
        for (int ni = 0; ni < 2; ++ni)
          acc[mi][ni] = mfma16(a[mi], bb[ni], acc[mi][ni]);
    }
    __syncthreads();
  }
  // ---- epilogue: restage O tile (64x256 f16) in LDS for coalesced stores ----
  h16* stg = &Bs[0][0];   // 64*264 = 16896 h16 <= 256*72 = 18432
  const int SW = 264;
  #pragma unroll
  for (int mi = 0; mi < 4; ++mi) {
    #pragma unroll
    for (int ni = 0; ni < 2; ++ni) {
      int col = wave * 32 + ni * 16 + l16;
      #pragma unroll
      for (int i = 0; i < 4; ++i) {
        int r = mi * 16 + quad * 4 + i;
        stg[r * SW + col] = (h16)acc[mi][ni][i];
      }
    }
  }
  __syncthreads();
  #pragma unroll
  for (int p = 0; p < 4; ++p) {
    int r = tid >> 3;
    int c = (tid & 7) * 8 + p * 64;
    h16x8 v = *(const h16x8*)&stg[r * SW + c];
    *(h16x8*)&oh[(row0 + r) * 256 + c] = v;
  }
}

extern "C" void kernel_launch(void* const* d_in, const int* in_sizes, int n_in,
                              void* d_out, int out_size, void* d_ws, size_t ws_size,
                              hipStream_t stream) {
  (void)in_sizes; (void)n_in; (void)out_size;
  const float* x   = (const float*)d_in[0];
  const float* qry = (const float*)d_in[1];
  const float* Wq  = (const float*)d_in[2];  const float* bq = (const float*)d_in[3];
  const float* Wk  = (const float*)d_in[4];  const float* bk = (const float*)d_in[5];
  const float* Wv  = (const float*)d_in[6];  const float* bv = (const float*)d_in[7];
  const float* W1  = (const float*)d_in[8];  const float* b1 = (const float*)d_in[9];
  const float* W2  = (const float*)d_in[10]; const float* b2 = (const float*)d_in[11];
  const float* W3  = (const float*)d_in[12]; const float* b3 = (const float*)d_in[13];

  float* outH = (float*)d_out;
  float* attn = outH + NQD;

  char* w = (char*)d_ws;
  h16* qh = (h16*)w;
  h16* kh = qh + NQD;
  h16* vT = kh + NQD;
  h16* oh = vT + NQD;
  h16* h1 = oh + NQD;
  h16* h2 = h1 + NQD;
  h16* wh = h2 + NQD;                               // 6 x 65536 h16
  size_t off_rs   = (size_t)(6 * NQD + 6 * 65536) * 2;   // 51,118,080
  size_t BASE     = off_rs + NROWS * 8;                  // 51,249,152
  size_t statsB   = NROWS * 32 * 8;                      // 4 MiB
  size_t ShB      = NROWS * NKK * 2;                     // 128 MiB

  bool modeA = ws_size >= BASE + statsB + ShB;
  bool modeB = !modeA && ws_size >= BASE + statsB;

  float2* stats = (modeA || modeB) ? (float2*)(w + BASE) : (float2*)h1;
  h16*    Sh    = modeA ? (h16*)(w + BASE + statsB) : nullptr;

  cast_weights<<<dim3(64, 6), 256, 0, stream>>>(Wq, Wk, Wv, W1, W2, W3, wh);
  qkv_proj<<<dim3(128, 4, 3), 256, 0, stream>>>(x, qry, wh, bq, bk, bv, qh, kh, vT);
  gemm_scores<<<dim3(32, 32, 4), 256, 0, stream>>>(qh, kh, stats, Sh, modeA ? nullptr : attn);
  if (modeA)
    gemm_av<h16><<<dim3(256), 512, 0, stream>>>(Sh, vT, stats, attn, oh);
  else
    gemm_av<float><<<dim3(256), 512, 0, stream>>>(attn, vT, stats, attn, oh);
  gemm256<<<dim3(128, 4), 256, 0, stream>>>(oh, wh + 3 * 65536, b1, h1, nullptr);
  gemm256<<<dim3(128, 4), 256, 0, stream>>>(h1, wh + 4 * 65536, b2, h2, nullptr);
  gemm256<<<dim3(128, 4), 256, 0, stream>>>(h2, wh + 5 * 65536, b3, nullptr, outH);
}